// Round 1
// baseline (299.239 us; speedup 1.0000x reference)
//
#include <hip/hip_runtime.h>
#include <hip/hip_bf16.h>

typedef __attribute__((ext_vector_type(8))) short short8;
typedef __attribute__((ext_vector_type(8))) unsigned short ushort8;
typedef __attribute__((ext_vector_type(4))) unsigned short ushort4v;
typedef __attribute__((ext_vector_type(4))) float floatx4;

#define DEVINL static __device__ __forceinline__

DEVINL float b2f(unsigned short s){ union{unsigned u; float f;} v; v.u=((unsigned)s)<<16; return v.f; }
DEVINL unsigned short f2b(float f){
  union{float f; unsigned u;} v; v.f=f; unsigned u=v.u;
  return (unsigned short)((u + 0x7fffu + ((u>>16)&1u))>>16);
}

constexpr int Bc=4, Sc=256, Hc=768, Nc=128, HIDc=1024, Lc=16;

// ---------------- gather + bf16 cast: con[b*N+n][768] ----------------
__global__ __launch_bounds__(256) void k_gather(const float* __restrict__ AH,
                                                const int* __restrict__ ST,
                                                unsigned short* __restrict__ con){
  int row = blockIdx.x;            // b*128 + n
  int b = row >> 7;
  int st = ST[row];
  const float* src = AH + ((size_t)(b*Sc + st))*Hc;
  unsigned short* dst = con + (size_t)row*Hc;
  int t = threadIdx.x;
  if (t < 192) {
    float4 v = reinterpret_cast<const float4*>(src)[t];
    ushort4v o = { f2b(v.x), f2b(v.y), f2b(v.z), f2b(v.w) };
    *reinterpret_cast<ushort4v*>(dst + 4*t) = o;
  }
}

// ---------- W1m (rows 2304..3071 of W1) -> bf16, MFMA-fragment order ----------
// layout: [hc(8)][ht(8)][kc(24)][lane(64)][e(8)], lane = col | (kseg<<4)
__global__ __launch_bounds__(256) void k_w1m(const float* __restrict__ W1,
                                             unsigned short* __restrict__ w1mF){
  int s = blockIdx.x*256 + threadIdx.x;   // 786432 total
  int k = s >> 10, h = s & 1023;
  float v = W1[(size_t)(2304 + k)*1024 + h];
  int hcb = h >> 7, hl = h & 127, ht = hl >> 4, col = hl & 15;
  int kc = k >> 5, kl = k & 31, kseg = kl >> 3, e = kl & 7;
  int ln = col | (kseg << 4);
  size_t off = ((size_t)((hcb*8 + ht)*24 + kc) << 9) + (size_t)(ln << 3) + e;
  w1mF[off] = f2b(v);
}

// ---------------- P/Q precompute ----------------
// P[row][h] = sum_k con[row][k]*(W1[k][h]+W1[1536+k][h])
// Q[row][h] = sum_k con[row][k]*(W1[768+k][h]-W1[1536+k][h])
__global__ __launch_bounds__(256) void k_pq(const unsigned short* __restrict__ con,
                                            const float* __restrict__ W1,
                                            float* __restrict__ P, float* __restrict__ Q){
  __shared__ float c_lds[16][768];
  int hcb = blockIdx.x >> 5, rg = blockIdx.x & 31;   // 8 h-chunks x 32 row-groups
  int row0 = rg*16;
  int t = threadIdx.x;
  for (int r = 0; r < 16; ++r)
    for (int k = t; k < 768; k += 256)
      c_lds[r][k] = b2f(con[(size_t)(row0 + r)*Hc + k]);
  __syncthreads();
  int h = hcb*128 + (t & 127);
  int rsel = (t >> 7) * 8;
  float aP[8] = {}, aQ[8] = {};
  for (int k4 = 0; k4 < 768; k4 += 4) {
    floatx4 cv[8];
    #pragma unroll
    for (int r = 0; r < 8; ++r) cv[r] = *reinterpret_cast<const floatx4*>(&c_lds[rsel + r][k4]);
    #pragma unroll
    for (int kk = 0; kk < 4; ++kk) {
      int k = k4 + kk;
      float w0  = W1[(size_t)k*1024 + h];
      float wd  = W1[(size_t)(1536 + k)*1024 + h];
      float wcc = W1[(size_t)(768 + k)*1024 + h];
      float wp = w0 + wd, wq = wcc - wd;
      #pragma unroll
      for (int r = 0; r < 8; ++r) {
        aP[r] = fmaf(cv[r][kk], wp, aP[r]);
        aQ[r] = fmaf(cv[r][kk], wq, aQ[r]);
      }
    }
  }
  #pragma unroll
  for (int r = 0; r < 8; ++r) {
    int gr = row0 + rsel + r;
    P[(size_t)gr*1024 + h] = aP[r];
    Q[(size_t)gr*1024 + h] = aQ[r];
  }
}

// ---------------- fused main kernel: one block per (b,i) ----------------
__global__ __launch_bounds__(256, 2) void k_main(const unsigned short* __restrict__ con,
    const unsigned short* __restrict__ w1mF,
    const float* __restrict__ P, const float* __restrict__ Q, const float* __restrict__ b1,
    const float* __restrict__ W2, const float* __restrict__ b2, float* __restrict__ out){
  __shared__ float a_row[768];
  __shared__ unsigned short A_lds[8][64][8];
  __shared__ unsigned short B_lds[8][64][8];
  __shared__ unsigned short hidF[8][4][64][8];   // [jtile][k2step][lane][e]
  __shared__ unsigned short W2_lds[4][64][8];

  int bi = blockIdx.x;                 // b*128 + i
  int b = bi >> 7, i = bi & 127;
  int t = threadIdx.x, w = t >> 6, lane = t & 63;
  int wr = w >> 1, wcq = w & 1;        // 2x2 wave grid
  int bN = b * Nc;
  int colh = lane & 15, rbase = (lane >> 4) << 2;

  for (int k = t; k < 768; k += 256) a_row[k] = b2f(con[(size_t)(bN + i)*Hc + k]);
  __syncthreads();

  floatx4 zero = {0.f, 0.f, 0.f, 0.f};
  floatx4 acc2[2] = {zero, zero};

  for (int hc = 0; hc < 8; ++hc) {
    floatx4 acc[4][4];
    #pragma unroll
    for (int m = 0; m < 4; ++m)
      #pragma unroll
      for (int n = 0; n < 4; ++n) acc[m][n] = zero;

    for (int kc = 0; kc < 24; ++kc) {
      int k0 = kc << 5;
      #pragma unroll
      for (int si = 0; si < 2; ++si) {
        int s = t + (si << 8);
        int jt = s >> 6, ln = s & 63;
        int j = (jt << 4) | (ln & 15);
        int gk = k0 + ((ln >> 4) << 3);
        ushort8 c8 = *reinterpret_cast<const ushort8*>(con + (size_t)(bN + j)*Hc + gk);
        ushort8 o;
        #pragma unroll
        for (int e = 0; e < 8; ++e) o[e] = f2b(a_row[gk + e] * b2f(c8[e]));
        *reinterpret_cast<ushort8*>(&A_lds[jt][ln][0]) = o;
        *reinterpret_cast<ushort8*>(&B_lds[jt][ln][0]) =
          *reinterpret_cast<const ushort8*>(w1mF + (((size_t)((hc*8 + jt)*24 + kc)) << 9) + (ln << 3));
      }
      __syncthreads();
      short8 af[4], bfr[4];
      #pragma unroll
      for (int m = 0; m < 4; ++m) af[m] = *reinterpret_cast<const short8*>(&A_lds[wr*4 + m][lane][0]);
      #pragma unroll
      for (int n = 0; n < 4; ++n) bfr[n] = *reinterpret_cast<const short8*>(&B_lds[wcq*4 + n][lane][0]);
      #pragma unroll
      for (int m = 0; m < 4; ++m)
        #pragma unroll
        for (int n = 0; n < 4; ++n)
          acc[m][n] = __builtin_amdgcn_mfma_f32_16x16x32_bf16(af[m], bfr[n], acc[m][n], 0, 0, 0);
      __syncthreads();
    }

    { // W2 chunk -> B2 fragment layout (one slot per thread)
      int ks = t >> 6, ln = t & 63;
      int ncol = ln & 15;
      int ghb = hc*128 + (ks << 5) + ((ln >> 4) << 3);
      ushort8 o;
      #pragma unroll
      for (int e = 0; e < 8; ++e) o[e] = f2b(W2[(size_t)(ghb + e)*Lc + ncol]);
      *reinterpret_cast<ushort8*>(&W2_lds[ks][ln][0]) = o;
    }

    float pb[4];
    #pragma unroll
    for (int n = 0; n < 4; ++n) {
      int gh = hc*128 + wcq*64 + n*16 + colh;
      pb[n] = P[(size_t)(bN + i)*HIDc + gh] + b1[gh];
    }
    #pragma unroll
    for (int m = 0; m < 4; ++m) {
      #pragma unroll
      for (int r = 0; r < 4; ++r) {
        int jl = wr*64 + m*16 + rbase + r;
        const float* qrow = Q + (size_t)(bN + jl)*HIDc + hc*128 + wcq*64;
        #pragma unroll
        for (int n = 0; n < 4; ++n) {
          float val = acc[m][n][r] + pb[n] + qrow[n*16 + colh];
          float ax = fabsf(val);
          float ex = __expf(-2.f*ax);
          float th = (1.f - ex)*__builtin_amdgcn_rcpf(1.f + ex);
          th = copysignf(th, val);
          int hl = wcq*64 + n*16 + colh;
          hidF[jl >> 4][hl >> 5][(jl & 15) | (((hl >> 3) & 3) << 4)][hl & 7] = f2b(th);
        }
      }
    }
    __syncthreads();
    #pragma unroll
    for (int jt2 = 0; jt2 < 2; ++jt2) {
      int jt = w*2 + jt2;
      #pragma unroll
      for (int ks = 0; ks < 4; ++ks) {
        short8 a2  = *reinterpret_cast<const short8*>(&hidF[jt][ks][lane][0]);
        short8 bb2 = *reinterpret_cast<const short8*>(&W2_lds[ks][lane][0]);
        acc2[jt2] = __builtin_amdgcn_mfma_f32_16x16x32_bf16(a2, bb2, acc2[jt2], 0, 0, 0);
      }
    }
    __syncthreads();
  }

  float bl = b2[colh];
  #pragma unroll
  for (int jt2 = 0; jt2 < 2; ++jt2) {
    int jt = w*2 + jt2;
    #pragma unroll
    for (int r = 0; r < 4; ++r) {
      int jl = jt*16 + rbase + r;
      out[((size_t)bi*Nc + jl)*Lc + colh] = acc2[jt2][r] + bl;
    }
  }
}

extern "C" void kernel_launch(void* const* d_in, const int* in_sizes, int n_in,
                              void* d_out, int out_size, void* d_ws, size_t ws_size,
                              hipStream_t stream) {
  const float* AH = (const float*)d_in[0];
  const int*   ST = (const int*)d_in[1];
  const float* W1 = (const float*)d_in[2];
  const float* b1 = (const float*)d_in[3];
  const float* W2 = (const float*)d_in[4];
  const float* b2 = (const float*)d_in[5];
  float* out = (float*)d_out;

  char* ws = (char*)d_ws;
  unsigned short* con  = (unsigned short*)ws;              //   786,432 B
  unsigned short* w1mF = (unsigned short*)(ws + 786432);   // 1,572,864 B
  float* P = (float*)(ws + 2359296);                       // 2,097,152 B
  float* Q = (float*)(ws + 4456448);                       // 2,097,152 B

  k_gather<<<512, 256, 0, stream>>>(AH, ST, con);
  k_w1m<<<3072, 256, 0, stream>>>(W1, w1mF);
  k_pq<<<256, 256, 0, stream>>>(con, W1, P, Q);
  k_main<<<512, 256, 0, stream>>>(con, w1mF, P, Q, b1, W2, b2, out);
}